// Round 9
// baseline (207.713 us; speedup 1.0000x reference)
//
#include <hip/hip_runtime.h>

// ---------------------------------------------------------------------------
// CMSFlipLinear: y = x @ W^T, W = ternary * per-128-group scales.
// Round 9: i8 path (R8 numerics, absmax 0.383) with the GEMM restructured for
// TLP overlap: 128x128 block tile, BK=128, 256 threads (4 waves, 64x64/wave),
// single-buffered 32 KiB LDS, m97-style {stage; vmcnt0; bar; read+mma; bar}.
// 3-4 blocks/CU co-resident -> independent blocks overlap each other's
// barrier/drain stalls (R8's 8-wave lockstep measured fully serialized:
// 5175 cyc/tile vs 4916 serialized model, MfmaUtil 42%).
// acc = pure-MFMA i32 (AGPR-resident, the R8 spill fix). Swizzle geometry
// identical to R8 (0 conflicts measured). M=8192, N=4096, K=4096.
// ---------------------------------------------------------------------------

typedef int intx4 __attribute__((ext_vector_type(4)));

constexpr int K  = 4096;
constexpr int N  = 4096;
constexpr int NG = 32;   // groups per output row = K/128

__device__ __forceinline__ void gload_lds16(const void* gsrc, void* ldst) {
  const __attribute__((address_space(1))) unsigned* g =
      reinterpret_cast<const __attribute__((address_space(1))) unsigned*>(
          reinterpret_cast<uintptr_t>(gsrc));
  __attribute__((address_space(3))) unsigned* l =
      reinterpret_cast<__attribute__((address_space(3))) unsigned*>(
          reinterpret_cast<uintptr_t>(ldst));
  __builtin_amdgcn_global_load_lds(g, l, 16, 0, 0);
}

// ---- prep 1: x -> i8 with per-row scale ------------------------------------
__global__ __launch_bounds__(256) void quant_x_kernel(const float* __restrict__ x,
                                                      char* __restrict__ q,
                                                      float* __restrict__ sx) {
  const int row = blockIdx.x;
  const int tid = threadIdx.x;
  const float4* xr = reinterpret_cast<const float4*>(x + (long)row * K);
  float4 v[4];
  float am = 0.f;
#pragma unroll
  for (int j = 0; j < 4; ++j) {
    v[j] = xr[tid * 4 + j];
    am = fmaxf(am, fmaxf(fmaxf(fabsf(v[j].x), fabsf(v[j].y)),
                         fmaxf(fabsf(v[j].z), fabsf(v[j].w))));
  }
#pragma unroll
  for (int off = 32; off > 0; off >>= 1)
    am = fmaxf(am, __shfl_xor(am, off));
  __shared__ float wmax[4];
  if ((tid & 63) == 0) wmax[tid >> 6] = am;
  __syncthreads();
  am = fmaxf(fmaxf(wmax[0], wmax[1]), fmaxf(wmax[2], wmax[3]));
  const float inv = am > 0.f ? 127.f / am : 0.f;
  int t[16];
#pragma unroll
  for (int j = 0; j < 4; ++j) {
    t[j * 4 + 0] = (int)rintf(v[j].x * inv);
    t[j * 4 + 1] = (int)rintf(v[j].y * inv);
    t[j * 4 + 2] = (int)rintf(v[j].z * inv);
    t[j * 4 + 3] = (int)rintf(v[j].w * inv);
  }
  int4 o;
  o.x = (t[0] & 255) | ((t[1] & 255) << 8) | ((t[2] & 255) << 16) | ((t[3] & 255) << 24);
  o.y = (t[4] & 255) | ((t[5] & 255) << 8) | ((t[6] & 255) << 16) | ((t[7] & 255) << 24);
  o.z = (t[8] & 255) | ((t[9] & 255) << 8) | ((t[10] & 255) << 16) | ((t[11] & 255) << 24);
  o.w = (t[12] & 255) | ((t[13] & 255) << 8) | ((t[14] & 255) << 16) | ((t[15] & 255) << 24);
  reinterpret_cast<int4*>(q + (long)row * K)[tid] = o;
  if (tid == 0) sx[row] = am * (1.f / 127.f);
}

// ---- prep 2: wq = tern * round(127*s/S_row); sw[row] = S_row/127 -----------
__global__ __launch_bounds__(256) void pack_w_kernel(const int* __restrict__ w,
                                                     const float* __restrict__ s,
                                                     char* __restrict__ o,
                                                     float* __restrict__ sw) {
  const int row = blockIdx.x;
  const int tid = threadIdx.x;
  __shared__ float Ssh;
  if (tid < 64) {
    float v = (tid < NG) ? s[(long)row * NG + tid] : 0.f;
#pragma unroll
    for (int off = 32; off > 0; off >>= 1)
      v = fmaxf(v, __shfl_xor(v, off));
    if (tid == 0) {
      Ssh = v;
      sw[row] = v * (1.f / 127.f);
    }
  }
  __syncthreads();
  const float S = Ssh;
  const int g = tid >> 3;  // 16 weights/thread -> group = tid*16/128
  const int m = (int)rintf(127.f * s[(long)row * NG + g] / S);
  const int4* src = reinterpret_cast<const int4*>(w + (long)row * K + tid * 16);
  int4 a = src[0], b = src[1], c = src[2], d = src[3];
  int4 r;
  r.x = ((a.x * m) & 255) | (((a.y * m) & 255) << 8) |
        (((a.z * m) & 255) << 16) | (((a.w * m) & 255) << 24);
  r.y = ((b.x * m) & 255) | (((b.y * m) & 255) << 8) |
        (((b.z * m) & 255) << 16) | (((b.w * m) & 255) << 24);
  r.z = ((c.x * m) & 255) | (((c.y * m) & 255) << 8) |
        (((c.z * m) & 255) << 16) | (((c.w * m) & 255) << 24);
  r.w = ((d.x * m) & 255) | (((d.y * m) & 255) << 8) |
        (((d.z * m) & 255) << 16) | (((d.w * m) & 255) << 24);
  reinterpret_cast<int4*>(o + (long)row * K)[tid] = r;
}

// ---------------------------------------------------------------------------
// GEMM LDS: As[16KiB] | Bs[16KiB], single-buffered. Tile rows = 128 B.
// Swizzle: byte = row*128 + (slot ^ ((row&7)<<4)), on ds_read AND on the
// global source of linear-dest global_load_lds (rule #21). Read geometry
// (16 rows x kq slots) measured 0 conflicts in R4/R6/R7/R8.
// ---------------------------------------------------------------------------

__device__ __forceinline__ intx4 ldfrag(const char* region, int row, int slot) {
  return *reinterpret_cast<const intx4*>(region + row * 128 +
                                         (slot ^ ((row & 7) << 4)));
}

// One staging round: 32 rows x 128 B = 4 KiB (256 thr x 16 B).
__device__ __forceinline__ void stage_round(const char* gmat, char* lregion,
                                            int k0, int rnd, int wid, int l) {
  const int row = rnd * 32 + wid * 8 + (l >> 3);
  const int col = ((l & 7) ^ ((l >> 3) & 7)) << 4;  // inverse-swizzled source
  const char* g = gmat + (long)row * K + k0 + col;
  char* ldst = lregion + rnd * 4096 + wid * 1024;   // + lane*16 by HW
  gload_lds16(g, ldst);
}

#define FENCE asm volatile("" ::: "memory")
#define BAR                       \
  do {                            \
    __builtin_amdgcn_s_barrier(); \
    FENCE;                        \
  } while (0)
#define VMCNT0 asm volatile("s_waitcnt vmcnt(0)" ::: "memory")

// 128x128x128-tile i8 GEMM, 4 waves (2Mx2N), 64x64 out per wave.
// Single LDS buffer; TLP (3-4 blocks/CU) provides the read/mma overlap.
__global__ __launch_bounds__(256, 3) void gemm_i8(
    const char* __restrict__ A, const char* __restrict__ B,
    const float* __restrict__ SW, const float* __restrict__ SX,
    float* __restrict__ C) {
  __shared__ char As[16384];
  __shared__ char Bs[16384];
  const int tid = threadIdx.x;
  const int wid = tid >> 6, l = tid & 63;
  const int wr = wid >> 1, wc = wid & 1;
  const int rlo = l & 15, kq = l >> 4;

  // T1: bijective XCD swizzle (2048 blocks, 2048%8==0). Consecutive swz
  // share the A row-strip (32 n-tiles per m) -> per-XCD L2 locality.
  const int wg = blockIdx.x;
  const int swz = (wg & 7) * 256 + (wg >> 3);
  const long brow = (long)(swz >> 5) * 128;  // 64 M-tiles
  const long bcol = (long)(swz & 31) * 128;  // 32 N-tiles

  const char* gA = A + brow * K;
  const char* gB = B + bcol * K;

  intx4 acc[4][4] = {};

#pragma unroll 1
  for (int t = 0; t < 32; ++t) {
    const int k0 = t << 7;
#pragma unroll
    for (int r = 0; r < 4; ++r) stage_round(gA, As, k0, r, wid, l);
#pragma unroll
    for (int r = 0; r < 4; ++r) stage_round(gB, Bs, k0, r, wid, l);
    VMCNT0;  // all 8 DMA writes landed (this wave); BAR covers other waves
    BAR;
#pragma unroll
    for (int ks = 0; ks < 2; ++ks) {
      intx4 af[4], bf[4];
#pragma unroll
      for (int mi = 0; mi < 4; ++mi)
        af[mi] = ldfrag(As, wr * 64 + mi * 16 + rlo, ks * 64 + kq * 16);
#pragma unroll
      for (int nt = 0; nt < 4; ++nt)
        bf[nt] = ldfrag(Bs, wc * 64 + nt * 16 + rlo, ks * 64 + kq * 16);
      __builtin_amdgcn_s_setprio(1);
#pragma unroll
      for (int mi = 0; mi < 4; ++mi)
#pragma unroll
        for (int nt = 0; nt < 4; ++nt)
          acc[mi][nt] = __builtin_amdgcn_mfma_i32_16x16x64_i8(
              af[mi], bf[nt], acc[mi][nt], 0, 0, 0);
      __builtin_amdgcn_s_setprio(0);
    }
    BAR;  // all waves' reads consumed -> next stage may overwrite
  }

  // Epilogue: y = acc * SX[row] * SW[col]. col = lane&15, row = kq*4 + r.
  const long crow0 = brow + wr * 64 + kq * 4;
  const long ccol = bcol + wc * 64 + rlo;
  float swn[4];
#pragma unroll
  for (int nt = 0; nt < 4; ++nt) swn[nt] = SW[ccol + nt * 16];
#pragma unroll
  for (int mi = 0; mi < 4; ++mi) {
    const float4 sx4 = *reinterpret_cast<const float4*>(SX + crow0 + mi * 16);
    const float sxr[4] = {sx4.x, sx4.y, sx4.z, sx4.w};
#pragma unroll
    for (int nt = 0; nt < 4; ++nt) {
      float* cp = C + (crow0 + mi * 16) * (long)N + ccol + nt * 16;
#pragma unroll
      for (int r = 0; r < 4; ++r)
        cp[r * N] = (float)acc[mi][nt][r] * sxr[r] * swn[nt];
    }
  }
}

// ---- fallback (only if workspace too small): naive fp32 --------------------
__global__ void fallback_kernel(const float* __restrict__ x,
                                const int* __restrict__ t,
                                const float* __restrict__ s,
                                float* __restrict__ y) {
  int n = blockIdx.x * 256 + threadIdx.x;
  int m = blockIdx.y;
  const int* tr = t + (long)n * K;
  const float* xr = x + (long)m * K;
  float acc = 0.f;
  for (int g = 0; g < K / 128; ++g) {
    float scv = s[n * (K / 128) + g];
    float part = 0.f;
#pragma unroll 4
    for (int k = g * 128; k < g * 128 + 128; ++k)
      part += xr[k] * (float)tr[k];
    acc += part * scv;
  }
  y[(long)m * N + n] = acc;
}

extern "C" void kernel_launch(void* const* d_in, const int* in_sizes, int n_in,
                              void* d_out, int out_size, void* d_ws,
                              size_t ws_size, hipStream_t stream) {
  const float* x = (const float*)d_in[0];
  const int* tern = (const int*)d_in[1];
  const float* scales = (const float*)d_in[2];
  float* out = (float*)d_out;

  const long M = (long)in_sizes[0] / K;  // 8192
  const size_t offW = (size_t)M * K;              // A_i8: 32 MiB
  const size_t offSW = offW + (size_t)N * K;      // W_i8: 16 MiB
  const size_t offSX = offSW + (size_t)N * 4;     // SW f32: 16 KiB
  const size_t need = offSX + (size_t)M * 4;      // SX f32: 32 KiB

  if (ws_size >= need && (M % 128) == 0) {
    char* Aq = (char*)d_ws;
    char* Wq = (char*)d_ws + offW;
    float* SW = (float*)((char*)d_ws + offSW);
    float* SX = (float*)((char*)d_ws + offSX);

    quant_x_kernel<<<(unsigned)M, 256, 0, stream>>>(x, Aq, SX);
    pack_w_kernel<<<(unsigned)N, 256, 0, stream>>>(tern, scales, Wq, SW);

    const unsigned nblk = (unsigned)((M / 128) * (N / 128));  // 2048
    gemm_i8<<<nblk, 256, 0, stream>>>(Aq, Wq, SW, SX, out);
  } else {
    dim3 grid(N / 256, (unsigned)M);
    fallback_kernel<<<grid, 256, 0, stream>>>(x, tern, scales, out);
  }
}